// Round 7
// baseline (535.623 us; speedup 1.0000x reference)
//
#include <hip/hip_runtime.h>

// Problem constants: B=16, S=2048, D=1024, P=8192, R=16, NL=64, span<=31
#define S_LEN      2048
#define D_DIM      1024
#define R_DIM      16
#define OUT_STRIDE 2064          // 2*D + R
#define NBUCK      8192          // (B*S)>>2 coarse sort buckets (32 KB LDS hist)
#define BPT        8             // buckets per thread in the scan (NBUCK/1024)
#define G          16            // sorted jobs per gather group
#define NSL        4             // column slices per group (256 floats each)
#define SLW        256           // slice width in floats

// ---------------------------------------------------------------------------
// Fused counting sort of the 2P span-jobs by coarse start bucket
// ((b*S + s) >> 2). One workgroup, everything in LDS.
__global__ __launch_bounds__(1024) void sort_jobs(
    const int* __restrict__ bidx, const int* __restrict__ e1s,
    const int* __restrict__ e2s, int* __restrict__ sorted, int njobs)
{
    __shared__ int hist[NBUCK];   // 32 KB
    __shared__ int part[1024];    // 4 KB
    const int t = threadIdx.x;

#pragma unroll
    for (int i = 0; i < BPT; ++i) hist[t * BPT + i] = 0;
    __syncthreads();

    for (int j = t; j < njobs; j += 1024) {
        const int p = j >> 1;
        const int s = (j & 1) ? e2s[p] : e1s[p];
        atomicAdd(&hist[(bidx[p] * S_LEN + s) >> 2], 1);
    }
    __syncthreads();

    int v[BPT];
    int sum = 0;
#pragma unroll
    for (int i = 0; i < BPT; ++i) { v[i] = hist[t * BPT + i]; sum += v[i]; }
    part[t] = sum;
    __syncthreads();
    for (int off = 1; off < 1024; off <<= 1) {
        int x = (t >= off) ? part[t - off] : 0;
        __syncthreads();
        part[t] += x;
        __syncthreads();
    }
    int run = (t == 0) ? 0 : part[t - 1];
#pragma unroll
    for (int i = 0; i < BPT; ++i) { int c = v[i]; hist[t * BPT + i] = run; run += c; }
    __syncthreads();

    for (int j = t; j < njobs; j += 1024) {
        const int p = j >> 1;
        const int s = (j & 1) ? e2s[p] : e1s[p];
        const int pos = atomicAdd(&hist[(bidx[p] * S_LEN + s) >> 2], 1);
        sorted[pos] = j;
    }
}

// ---------------------------------------------------------------------------
// Grouped gather v10: G=16 traffic (264 MB window traffic, confirmed twice
// via FETCH=109 MB) at v4-level request pressure. Supply law from v3-v9:
// throughput = outstanding-bytes / latency; v4 sustained ~8 TB/s with
// 20 waves/CU x 1KB requests; v9 collapsed to 2.3 TB/s with float2 loads
// and VGPR clamped to 36 (4th clamp incident: 48/32/64-spill/36).
// Fix: amdgpu_waves_per_eu(4,5) -- max=5 tells regalloc NOT to optimize
// past 5 waves/EU, freeing ~102 VGPRs without the clamp-then-spill.
// Demand: acc[16]xfloat4 = 64 + cur[4] = 16 + addressing ~ 95. Structure:
// single-wave 64-thread blocks, NO LDS, NO barriers, 4 col-slices of 256
// floats -> 4096 independent blocks (16/CU, all resident). Per iter:
// 4 independent 1KB float4 loads, then 256 v_fmac (512 cy) with all-SGPR
// weight selects (SALU, parallel pipe). Out-of-window rows weight 0;
// tail rows clamped to the last window row.
__global__ __attribute__((amdgpu_flat_work_group_size(64, 64),
                          amdgpu_waves_per_eu(4, 5)))
void gather_g16v4(
    const float* __restrict__ tok,     // [B*S, D] fp32
    const int*   __restrict__ sorted,  // [2P] sorted job ids
    const int*   __restrict__ bidx,
    const int*   __restrict__ e1s, const int* __restrict__ e1e,
    const int*   __restrict__ e2s, const int* __restrict__ e2e,
    const int*   __restrict__ ridx,
    const float* __restrict__ rtab,    // [NL, R]
    float*       __restrict__ out)     // [P, 2D+R]
{
    const int blk = blockIdx.x;
    // XCD swizzle: contiguous work ranges per XCD (grid 4096, %8==0, bijective)
    const int w  = (blk & 7) * (gridDim.x >> 3) + (blk >> 3);
    const int g  = w >> 2;             // job group (16 sorted jobs)
    const int sl = w & 3;              // col slice: floats [sl*256, sl*256+256)
    const int ln = threadIdx.x;        // 0..63, 4 cols each

    // group metadata -> SGPRs: start, length, 1/length (48 scalar regs)
    int   js[G], jlen[G];
    float jw[G];
    int mins = 0x7fffffff, maxe = 0;
#pragma unroll
    for (int i = 0; i < G; ++i) {
        const int id = __builtin_amdgcn_readfirstlane(sorted[g * G + i]);
        const int p  = id >> 1;
        const int h  = id & 1;
        const int b  = __builtin_amdgcn_readfirstlane(bidx[p]);
        const int s  = __builtin_amdgcn_readfirstlane(h ? e2s[p] : e1s[p]);
        const int e  = __builtin_amdgcn_readfirstlane(h ? e2e[p] : e1e[p]);
        js[i]   = b * S_LEN + s;
        jlen[i] = e - s;
        jw[i]   = 1.0f / (float)(e - s);
        mins = min(mins, js[i]);
        maxe = max(maxe, b * S_LEN + e);
    }

    const int nrows = maxe - mins;             // >= 1
    const int rmax  = nrows - 1;
    const int niter = (nrows + 3) >> 2;

    // float4 row stride = D/4 = 256; lane's col = sl*256 + ln*4
    const float4* base = reinterpret_cast<const float4*>(tok) +
                         (size_t)mins * (D_DIM / 4) + sl * (SLW / 4) + ln;

    float4 acc[G];
#pragma unroll
    for (int i = 0; i < G; ++i) acc[i] = make_float4(0.f, 0.f, 0.f, 0.f);

    for (int it = 0; it < niter; ++it) {
        const int r0 = it * 4;
        float4 cur[4];                          // 4 independent 1KB wave-loads
#pragma unroll
        for (int k = 0; k < 4; ++k)
            cur[k] = base[(size_t)min(r0 + k, rmax) * (D_DIM / 4)];

        const int gr = mins + r0;
#pragma unroll
        for (int i = 0; i < G; ++i) {           // all-SGPR weight selects
            const float w0 = ((unsigned)(gr + 0 - js[i]) < (unsigned)jlen[i]) ? jw[i] : 0.f;
            const float w1 = ((unsigned)(gr + 1 - js[i]) < (unsigned)jlen[i]) ? jw[i] : 0.f;
            const float w2 = ((unsigned)(gr + 2 - js[i]) < (unsigned)jlen[i]) ? jw[i] : 0.f;
            const float w3 = ((unsigned)(gr + 3 - js[i]) < (unsigned)jlen[i]) ? jw[i] : 0.f;
            acc[i].x += cur[0].x * w0 + cur[1].x * w1 + cur[2].x * w2 + cur[3].x * w3;
            acc[i].y += cur[0].y * w0 + cur[1].y * w1 + cur[2].y * w2 + cur[3].y * w3;
            acc[i].z += cur[0].z * w0 + cur[1].z * w1 + cur[2].z * w2 + cur[3].z * w3;
            acc[i].w += cur[0].w * w0 + cur[1].w * w1 + cur[2].w * w2 + cur[3].w * w3;
        }
    }

    // epilogue: recompute output metadata (scalar L2 re-reads, saves regs)
#pragma unroll
    for (int i = 0; i < G; ++i) {
        const int id = __builtin_amdgcn_readfirstlane(sorted[g * G + i]);
        const int p  = id >> 1;
        const int h  = id & 1;
        float* dst = out + (size_t)p * OUT_STRIDE + h * D_DIM + sl * SLW + ln * 4;
        *reinterpret_cast<float4*>(dst) = acc[i];
        if (sl == 0 && h == 0 && ln < 4) {      // rel row once per pair
            const float4 rv = *reinterpret_cast<const float4*>(
                rtab + ridx[p] * R_DIM + ln * 4);
            *reinterpret_cast<float4*>(
                out + (size_t)p * OUT_STRIDE + 2 * D_DIM + ln * 4) = rv;
        }
    }
}

// ---------------------------------------------------------------------------
extern "C" void kernel_launch(void* const* d_in, const int* in_sizes, int n_in,
                              void* d_out, int out_size, void* d_ws, size_t ws_size,
                              hipStream_t stream) {
    const float* tok  = (const float*)d_in[0];
    const int*   bidx = (const int*)d_in[1];
    const int*   e1s  = (const int*)d_in[2];
    const int*   e1e  = (const int*)d_in[3];
    const int*   e2s  = (const int*)d_in[4];
    const int*   e2e  = (const int*)d_in[5];
    const int*   ridx = (const int*)d_in[6];
    const float* rtab = (const float*)d_in[7];
    float*       out  = (float*)d_out;

    const int P     = in_sizes[1];   // 8192
    const int njobs = 2 * P;         // 16384

    int* sorted = (int*)d_ws;        // njobs ints

    sort_jobs<<<1, 1024, 0, stream>>>(bidx, e1s, e2s, sorted, njobs);

    const int nblocks = (njobs / G) * NSL;      // 1024 groups x 4 slices = 4096
    gather_g16v4<<<nblocks, 64, 0, stream>>>(
        tok, sorted, bidx, e1s, e1e, e2s, e2e, ridx, rtab, out);
}

// Round 8
// 320.823 us; speedup vs baseline: 1.6695x; 1.6695x over previous
//
#include <hip/hip_runtime.h>

// Problem constants: B=16, S=2048, D=1024, P=8192, R=16, NL=64, span<=31
#define S_LEN      2048
#define D_DIM      1024
#define R_DIM      16
#define OUT_STRIDE 2064          // 2*D + R
#define NBUCK      8192          // (B*S)>>2 coarse sort buckets (32 KB LDS hist)
#define BPT        8             // buckets per thread in the scan (NBUCK/1024)
#define G          16            // sorted jobs per gather group
#define NSL        4             // column slices per group
#define SLW        256           // slice width in floats (1 float per thread)

// ---------------------------------------------------------------------------
// Fused counting sort of the 2P span-jobs by coarse start bucket
// ((b*S + s) >> 2). One workgroup, everything in LDS.
__global__ __launch_bounds__(1024) void sort_jobs(
    const int* __restrict__ bidx, const int* __restrict__ e1s,
    const int* __restrict__ e2s, int* __restrict__ sorted, int njobs)
{
    __shared__ int hist[NBUCK];   // 32 KB
    __shared__ int part[1024];    // 4 KB
    const int t = threadIdx.x;

#pragma unroll
    for (int i = 0; i < BPT; ++i) hist[t * BPT + i] = 0;
    __syncthreads();

    for (int j = t; j < njobs; j += 1024) {
        const int p = j >> 1;
        const int s = (j & 1) ? e2s[p] : e1s[p];
        atomicAdd(&hist[(bidx[p] * S_LEN + s) >> 2], 1);
    }
    __syncthreads();

    int v[BPT];
    int sum = 0;
#pragma unroll
    for (int i = 0; i < BPT; ++i) { v[i] = hist[t * BPT + i]; sum += v[i]; }
    part[t] = sum;
    __syncthreads();
    for (int off = 1; off < 1024; off <<= 1) {
        int x = (t >= off) ? part[t - off] : 0;
        __syncthreads();
        part[t] += x;
        __syncthreads();
    }
    int run = (t == 0) ? 0 : part[t - 1];
#pragma unroll
    for (int i = 0; i < BPT; ++i) { int c = v[i]; hist[t * BPT + i] = run; run += c; }
    __syncthreads();

    for (int j = t; j < njobs; j += 1024) {
        const int p = j >> 1;
        const int s = (j & 1) ? e2s[p] : e1s[p];
        const int pos = atomicAdd(&hist[(bidx[p] * S_LEN + s) >> 2], 1);
        sorted[pos] = j;
    }
}

// ---------------------------------------------------------------------------
// Grouped gather v11: ONE COLUMN PER THREAD. Root cause of every G=16
// failure (5 regalloc-clamp incidents: VGPR 48/32/64-spill/36/64-spill):
// acc register demand = G x floats-per-thread, and 4 floats/thread needs
// 64 acc VGPRs -- above what hipcc will grant without spilling. Here:
// 256-thread blocks, each thread owns ONE float column -> acc[16] = 16
// VGPRs, cur[4]+nxt[4] = 8, total ~40 -> fits the 8-wave/SIMD tier
// NATURALLY. No LDS, no barriers, threads fully independent. Loads are
// dword (256 B/wave-instr, full 64B sectors, 100% coalesced); at the
// ~8 TB/s supply target that is 0.5 vmem-instr/cyc/CU -- under TA limit.
// Grid: 1024 groups x 4 slices x 4 waves = 16384 independent waves.
// G=16 window traffic = 258 MB (confirmed via FETCH=109 MB twice) vs
// 640 MB at G=4 -> supply floor ~40 us at the 8 TB/s observed ceiling.
// Weight selects are all-SGPR (s_cselect feeding v_fmac's SGPR operand);
// out-of-window rows get weight 0; tail rows clamped to last window row.
__global__ __launch_bounds__(256) void gather_sc(
    const float* __restrict__ tok,     // [B*S, D] fp32
    const int*   __restrict__ sorted,  // [2P] sorted job ids
    const int*   __restrict__ bidx,
    const int*   __restrict__ e1s, const int* __restrict__ e1e,
    const int*   __restrict__ e2s, const int* __restrict__ e2e,
    const int*   __restrict__ ridx,
    const float* __restrict__ rtab,    // [NL, R]
    float*       __restrict__ out)     // [P, 2D+R]
{
    const int blk = blockIdx.x;
    // XCD swizzle: contiguous work ranges per XCD (grid 4096, %8==0, bijective)
    const int w  = (blk & 7) * (gridDim.x >> 3) + (blk >> 3);
    const int g  = w >> 2;             // job group (16 sorted jobs)
    const int sl = w & 3;              // col slice: floats [sl*256, sl*256+256)
    const int t  = threadIdx.x;        // 0..255, ONE col each

    // group metadata -> SGPRs: start, length, 1/length (48 scalar regs)
    int   js[G], jlen[G];
    float jw[G];
    int mins = 0x7fffffff, maxe = 0;
#pragma unroll
    for (int i = 0; i < G; ++i) {
        const int id = __builtin_amdgcn_readfirstlane(sorted[g * G + i]);
        const int p  = id >> 1;
        const int h  = id & 1;
        const int b  = __builtin_amdgcn_readfirstlane(bidx[p]);
        const int s  = __builtin_amdgcn_readfirstlane(h ? e2s[p] : e1s[p]);
        const int e  = __builtin_amdgcn_readfirstlane(h ? e2e[p] : e1e[p]);
        js[i]   = b * S_LEN + s;
        jlen[i] = e - s;
        jw[i]   = 1.0f / (float)(e - s);
        mins = min(mins, js[i]);
        maxe = max(maxe, b * S_LEN + e);
    }

    const int nrows = maxe - mins;             // >= 1
    const int rmax  = nrows - 1;
    const int niter = (nrows + 3) >> 2;

    // lane's column = sl*256 + t; row stride = D floats
    const float* base = tok + (size_t)mins * D_DIM + sl * SLW + t;

    float acc[G];
#pragma unroll
    for (int i = 0; i < G; ++i) acc[i] = 0.f;

    float cur[4];
#pragma unroll
    for (int k = 0; k < 4; ++k)
        cur[k] = base[(size_t)min(k, rmax) * D_DIM];

    for (int it = 0; it < niter; ++it) {
        const int r0 = it * 4;
        float nxt[4];                           // next 4 rows (clamped)
#pragma unroll
        for (int k = 0; k < 4; ++k)
            nxt[k] = base[(size_t)min(r0 + 4 + k, rmax) * D_DIM];

        const int gr = mins + r0;
#pragma unroll
        for (int i = 0; i < G; ++i) {           // all-SGPR weight selects
            const float w0 = ((unsigned)(gr + 0 - js[i]) < (unsigned)jlen[i]) ? jw[i] : 0.f;
            const float w1 = ((unsigned)(gr + 1 - js[i]) < (unsigned)jlen[i]) ? jw[i] : 0.f;
            const float w2 = ((unsigned)(gr + 2 - js[i]) < (unsigned)jlen[i]) ? jw[i] : 0.f;
            const float w3 = ((unsigned)(gr + 3 - js[i]) < (unsigned)jlen[i]) ? jw[i] : 0.f;
            acc[i] += cur[0] * w0 + cur[1] * w1 + cur[2] * w2 + cur[3] * w3;
        }
#pragma unroll
        for (int k = 0; k < 4; ++k) cur[k] = nxt[k];
    }

    // epilogue: recompute output metadata (scalar L2 re-reads, saves regs)
#pragma unroll
    for (int i = 0; i < G; ++i) {
        const int id = __builtin_amdgcn_readfirstlane(sorted[g * G + i]);
        const int p  = id >> 1;
        const int h  = id & 1;
        out[(size_t)p * OUT_STRIDE + h * D_DIM + sl * SLW + t] = acc[i];
        if (sl == 0 && h == 0 && t < R_DIM) {   // rel row once per pair
            out[(size_t)p * OUT_STRIDE + 2 * D_DIM + t] =
                rtab[ridx[p] * R_DIM + t];
        }
    }
}

// ---------------------------------------------------------------------------
extern "C" void kernel_launch(void* const* d_in, const int* in_sizes, int n_in,
                              void* d_out, int out_size, void* d_ws, size_t ws_size,
                              hipStream_t stream) {
    const float* tok  = (const float*)d_in[0];
    const int*   bidx = (const int*)d_in[1];
    const int*   e1s  = (const int*)d_in[2];
    const int*   e1e  = (const int*)d_in[3];
    const int*   e2s  = (const int*)d_in[4];
    const int*   e2e  = (const int*)d_in[5];
    const int*   ridx = (const int*)d_in[6];
    const float* rtab = (const float*)d_in[7];
    float*       out  = (float*)d_out;

    const int P     = in_sizes[1];   // 8192
    const int njobs = 2 * P;         // 16384

    int* sorted = (int*)d_ws;        // njobs ints

    sort_jobs<<<1, 1024, 0, stream>>>(bidx, e1s, e2s, sorted, njobs);

    const int nblocks = (njobs / G) * NSL;      // 1024 groups x 4 slices = 4096
    gather_sc<<<nblocks, 256, 0, stream>>>(
        tok, sorted, bidx, e1s, e1e, e2s, e2e, ridx, rtab, out);
}